// Round 5
// baseline (138.489 us; speedup 1.0000x reference)
//
#include <hip/hip_runtime.h>
#include <hip/hip_bf16.h>
#include <hip/hip_cooperative_groups.h>
#include <math.h>

namespace cg = cooperative_groups;

// NCM classifier: B=1024, C=500, F=512 (fp32 in/out).
//   xs = x / variance[0]
//   dist[b][c] = sqrt(sum_f (xs[b][f] - means[c][f])^2)
//   out = concat(softmax(-dist, axis=1), -dist, dist)   // each [B][C]
//
// dist^2 = ||xs||^2 + ||m||^2 - 2*(xs.m), cross term via bf16 MFMA.
// Single cooperative kernel: phase1 convert-once fp32->bf16 + norms (ws),
// grid.sync, phase2 16x16 MFMA distance tiles, grid.sync, phase3 softmax.
#define NB 1024
#define NC 500
#define NCP 512
#define NF 512

typedef __attribute__((ext_vector_type(8))) short bf16x8;
typedef __attribute__((ext_vector_type(4))) float f32x4;

union bfpack { bf16x8 v; __hip_bfloat162 h[4]; };

// ---- device helpers -------------------------------------------------------

// convert one fp32 row (NF) to bf16 with scale, write row norm (lane 0)
static __device__ inline void prep_row(const float* __restrict__ src,
                                       ushort* __restrict__ dst,
                                       float* __restrict__ nrm,
                                       float scale, bool zero, int lane)
{
    float4 v0, v1;
    if (!zero) {
        v0 = *reinterpret_cast<const float4*>(&src[lane * 8]);
        v1 = *reinterpret_cast<const float4*>(&src[lane * 8 + 4]);
        v0.x *= scale; v0.y *= scale; v0.z *= scale; v0.w *= scale;
        v1.x *= scale; v1.y *= scale; v1.z *= scale; v1.w *= scale;
    } else {
        v0 = make_float4(0.f, 0.f, 0.f, 0.f);
        v1 = v0;
    }
    bfpack p;
    p.h[0] = __float22bfloat162_rn(make_float2(v0.x, v0.y));
    p.h[1] = __float22bfloat162_rn(make_float2(v0.z, v0.w));
    p.h[2] = __float22bfloat162_rn(make_float2(v1.x, v1.y));
    p.h[3] = __float22bfloat162_rn(make_float2(v1.z, v1.w));
    *reinterpret_cast<bf16x8*>(&dst[lane * 8]) = p.v;

    float s = v0.x * v0.x + v0.y * v0.y + v0.z * v0.z + v0.w * v0.w
            + v1.x * v1.x + v1.y * v1.y + v1.z * v1.z + v1.w * v1.w;
    #pragma unroll
    for (int off = 32; off > 0; off >>= 1) s += __shfl_xor(s, off, 64);
    if (lane == 0) *nrm = s;
}

// one 16x16 distance tile: tile id `wid` in [0, 2048): b0=(wid>>5)*16, c0=(wid&31)*16
static __device__ inline void dist_tile(int wid, int lane,
                                        const ushort* __restrict__ xb,
                                        const ushort* __restrict__ mb,
                                        const float* __restrict__ nx,
                                        const float* __restrict__ nm,
                                        float* __restrict__ out)
{
    const int fr = lane & 15;
    const int g  = lane >> 4;
    const int b0 = (wid >> 5) * 16;
    const int c0 = (wid & 31) * 16;
    const ushort* ap = xb + (size_t)(b0 + fr) * NF + g * 8;
    const ushort* bp = mb + (size_t)(c0 + fr) * NF + g * 8;

    f32x4 acc = {0.f, 0.f, 0.f, 0.f};
    #pragma unroll 4
    for (int k = 0; k < NF; k += 32) {
        bf16x8 a = *reinterpret_cast<const bf16x8*>(ap + k);
        bf16x8 b = *reinterpret_cast<const bf16x8*>(bp + k);
        acc = __builtin_amdgcn_mfma_f32_16x16x32_bf16(a, b, acc, 0, 0, 0);
    }
    // C/D layout (m89/m91): col = lane&15, row = (lane>>4)*4 + reg
    const int c = c0 + fr;
    if (c < NC) {
        const float nmc = nm[c];
        float* expo  = out + (size_t)NB * NC;
        float* cdiff = out + (size_t)2 * NB * NC;
        #pragma unroll
        for (int r = 0; r < 4; ++r) {
            int b = b0 + g * 4 + r;
            float d2 = nx[b] + nmc - 2.0f * acc[r];
            float d = sqrtf(fmaxf(d2, 0.0f));
            expo[(size_t)b * NC + c]  = -d;
            cdiff[(size_t)b * NC + c] = d;
        }
    }
}

// softmax over one row of NC=500, one wave; row base (b*500*4B) is 16B-aligned
static __device__ inline void softmax_row(const float* __restrict__ expo,
                                          float* __restrict__ probs, int lane)
{
    const int base = lane * 8;
    const bool val0 = base + 3 < NC;
    const bool val1 = base + 7 < NC;
    const float4 ninf = make_float4(-1e30f, -1e30f, -1e30f, -1e30f);

    float4 v0 = val0 ? *reinterpret_cast<const float4*>(&expo[base])     : ninf;
    float4 v1 = val1 ? *reinterpret_cast<const float4*>(&expo[base + 4]) : ninf;

    float m = fmaxf(fmaxf(fmaxf(v0.x, v0.y), fmaxf(v0.z, v0.w)),
                    fmaxf(fmaxf(v1.x, v1.y), fmaxf(v1.z, v1.w)));
    #pragma unroll
    for (int off = 32; off > 0; off >>= 1)
        m = fmaxf(m, __shfl_xor(m, off, 64));

    float4 e0, e1;
    e0.x = expf(v0.x - m); e0.y = expf(v0.y - m);
    e0.z = expf(v0.z - m); e0.w = expf(v0.w - m);
    e1.x = expf(v1.x - m); e1.y = expf(v1.y - m);
    e1.z = expf(v1.z - m); e1.w = expf(v1.w - m);

    float s = e0.x + e0.y + e0.z + e0.w + e1.x + e1.y + e1.z + e1.w;
    #pragma unroll
    for (int off = 32; off > 0; off >>= 1)
        s += __shfl_xor(s, off, 64);
    float inv = 1.0f / s;

    e0.x *= inv; e0.y *= inv; e0.z *= inv; e0.w *= inv;
    e1.x *= inv; e1.y *= inv; e1.z *= inv; e1.w *= inv;

    if (val0) *reinterpret_cast<float4*>(&probs[base])     = e0;
    if (val1) *reinterpret_cast<float4*>(&probs[base + 4]) = e1;
}

// ---- single cooperative kernel: 512 blocks x 256 thr = 2048 waves ----------
__global__ __launch_bounds__(256) void ncm_fused_kernel(
    const float* __restrict__ x, const float* __restrict__ means,
    const float* __restrict__ variance, float* __restrict__ out,
    ushort* __restrict__ xb, ushort* __restrict__ mb,
    float* __restrict__ nx, float* __restrict__ nm)
{
    cg::grid_group gg = cg::this_grid();
    const int lane = threadIdx.x & 63;
    const int wid  = blockIdx.x * 4 + (threadIdx.x >> 6);  // 0..2047
    const float inv_var = 1.0f / variance[0];

    // phase 1: convert once (x rows 0..1023, means rows 0..511 zero-padded)
    if (wid < NB) {
        prep_row(x + (size_t)wid * NF, xb + (size_t)wid * NF, nx + wid,
                 inv_var, false, lane);
    } else if (wid < NB + NCP) {
        int c = wid - NB;
        prep_row(means + (size_t)c * NF, mb + (size_t)c * NF, nm + c,
                 1.0f, c >= NC, lane);
    }
    gg.sync();

    // phase 2: 2048 distance tiles of 16x16, one per wave
    dist_tile(wid, lane, xb, mb, nx, nm, out);
    gg.sync();

    // phase 3: softmax, one wave per row
    if (wid < NB)
        softmax_row(out + (size_t)NB * NC + (size_t)wid * NC,
                    out + (size_t)wid * NC, lane);
}

// ---- fallback A: 3-kernel ws path (if cooperative launch unavailable) -----
__global__ __launch_bounds__(256) void ncm_prep_kernel(
    const float* __restrict__ x, const float* __restrict__ means,
    const float* __restrict__ variance,
    ushort* __restrict__ xb, ushort* __restrict__ mb,
    float* __restrict__ nx, float* __restrict__ nm)
{
    const int lane = threadIdx.x & 63;
    const int wid  = blockIdx.x * 4 + (threadIdx.x >> 6);  // 0..1535
    const float inv_var = 1.0f / variance[0];
    if (wid < NB)
        prep_row(x + (size_t)wid * NF, xb + (size_t)wid * NF, nx + wid,
                 inv_var, false, lane);
    else {
        int c = wid - NB;
        prep_row(means + (size_t)c * NF, mb + (size_t)c * NF, nm + c,
                 1.0f, c >= NC, lane);
    }
}

__global__ __launch_bounds__(64) void ncm_gemm_kernel(
    const ushort* __restrict__ xb, const ushort* __restrict__ mb,
    const float* __restrict__ nx, const float* __restrict__ nm,
    float* __restrict__ out)
{
    dist_tile(blockIdx.x, threadIdx.x, xb, mb, nx, nm, out);
}

__global__ __launch_bounds__(64) void ncm_softmax_kernel(float* __restrict__ out)
{
    softmax_row(out + (size_t)NB * NC + (size_t)blockIdx.x * NC,
                out + (size_t)blockIdx.x * NC, threadIdx.x);
}

// ---- fallback B: no-ws fused dist (proven in R4) ---------------------------
static __device__ inline bf16x8 cvt8(float4 u0, float4 u1, float scale, float& nacc) {
    u0.x *= scale; u0.y *= scale; u0.z *= scale; u0.w *= scale;
    u1.x *= scale; u1.y *= scale; u1.z *= scale; u1.w *= scale;
    bfpack p;
    p.h[0] = __float22bfloat162_rn(make_float2(u0.x, u0.y));
    p.h[1] = __float22bfloat162_rn(make_float2(u0.z, u0.w));
    p.h[2] = __float22bfloat162_rn(make_float2(u1.x, u1.y));
    p.h[3] = __float22bfloat162_rn(make_float2(u1.z, u1.w));
    nacc = fmaf(u0.x, u0.x, nacc); nacc = fmaf(u0.y, u0.y, nacc);
    nacc = fmaf(u0.z, u0.z, nacc); nacc = fmaf(u0.w, u0.w, nacc);
    nacc = fmaf(u1.x, u1.x, nacc); nacc = fmaf(u1.y, u1.y, nacc);
    nacc = fmaf(u1.z, u1.z, nacc); nacc = fmaf(u1.w, u1.w, nacc);
    return p.v;
}

__global__ __launch_bounds__(64) void ncm_dist_nows_kernel(
    const float* __restrict__ x, const float* __restrict__ means,
    const float* __restrict__ variance, float* __restrict__ out)
{
    const int lane = threadIdx.x;
    const int g  = lane >> 4;
    const int fr = lane & 15;
    const int b0 = blockIdx.x * 32;
    const int c0 = blockIdx.y * 32;
    const float inv_var = 1.0f / variance[0];

    const float* pa0 = x + (size_t)(b0 + fr) * NF + g * 8;
    const float* pa1 = pa0 + (size_t)16 * NF;
    const int cB0 = c0 + fr, cB1 = cB0 + 16;
    const bool vB0 = cB0 < NC, vB1 = cB1 < NC;
    const float* pb0 = means + (size_t)cB0 * NF + g * 8;
    const float* pb1 = means + (size_t)cB1 * NF + g * 8;

    f32x4 acc00 = {0.f, 0.f, 0.f, 0.f};
    f32x4 acc01 = acc00, acc10 = acc00, acc11 = acc00;
    float na0 = 0.f, na1 = 0.f, nb0 = 0.f, nb1 = 0.f;
    const float4 z4 = make_float4(0.f, 0.f, 0.f, 0.f);

    #pragma unroll 4
    for (int k = 0; k < NF; k += 32) {
        float4 a0lo = *reinterpret_cast<const float4*>(pa0 + k);
        float4 a0hi = *reinterpret_cast<const float4*>(pa0 + k + 4);
        float4 a1lo = *reinterpret_cast<const float4*>(pa1 + k);
        float4 a1hi = *reinterpret_cast<const float4*>(pa1 + k + 4);
        float4 b0lo = vB0 ? *reinterpret_cast<const float4*>(pb0 + k)     : z4;
        float4 b0hi = vB0 ? *reinterpret_cast<const float4*>(pb0 + k + 4) : z4;
        float4 b1lo = vB1 ? *reinterpret_cast<const float4*>(pb1 + k)     : z4;
        float4 b1hi = vB1 ? *reinterpret_cast<const float4*>(pb1 + k + 4) : z4;

        bf16x8 fa0 = cvt8(a0lo, a0hi, inv_var, na0);
        bf16x8 fa1 = cvt8(a1lo, a1hi, inv_var, na1);
        bf16x8 fb0 = cvt8(b0lo, b0hi, 1.0f, nb0);
        bf16x8 fb1 = cvt8(b1lo, b1hi, 1.0f, nb1);

        acc00 = __builtin_amdgcn_mfma_f32_16x16x32_bf16(fa0, fb0, acc00, 0, 0, 0);
        acc01 = __builtin_amdgcn_mfma_f32_16x16x32_bf16(fa0, fb1, acc01, 0, 0, 0);
        acc10 = __builtin_amdgcn_mfma_f32_16x16x32_bf16(fa1, fb0, acc10, 0, 0, 0);
        acc11 = __builtin_amdgcn_mfma_f32_16x16x32_bf16(fa1, fb1, acc11, 0, 0, 0);
    }

    na0 += __shfl_xor(na0, 16, 64); na0 += __shfl_xor(na0, 32, 64);
    na1 += __shfl_xor(na1, 16, 64); na1 += __shfl_xor(na1, 32, 64);
    nb0 += __shfl_xor(nb0, 16, 64); nb0 += __shfl_xor(nb0, 32, 64);
    nb1 += __shfl_xor(nb1, 16, 64); nb1 += __shfl_xor(nb1, 32, 64);

    const int rg = g * 4;
    float nxr0[4], nxr1[4];
    #pragma unroll
    for (int r = 0; r < 4; ++r) {
        nxr0[r] = __shfl(na0, rg + r, 64);
        nxr1[r] = __shfl(na1, rg + r, 64);
    }

    float* expo  = out + (size_t)NB * NC;
    float* cdiff = out + (size_t)2 * NB * NC;
    #pragma unroll
    for (int wm = 0; wm < 2; ++wm) {
        f32x4 g_lo = wm ? acc10 : acc00;
        f32x4 g_hi = wm ? acc11 : acc01;
        #pragma unroll
        for (int r = 0; r < 4; ++r) {
            int b = b0 + wm * 16 + rg + r;
            float nxb = wm ? nxr1[r] : nxr0[r];
            if (vB0) {
                float d = sqrtf(fmaxf(nxb + nb0 - 2.0f * g_lo[r], 0.0f));
                expo[(size_t)b * NC + cB0]  = -d;
                cdiff[(size_t)b * NC + cB0] = d;
            }
            if (vB1) {
                float d = sqrtf(fmaxf(nxb + nb1 - 2.0f * g_hi[r], 0.0f));
                expo[(size_t)b * NC + cB1]  = -d;
                cdiff[(size_t)b * NC + cB1] = d;
            }
        }
    }
}

extern "C" void kernel_launch(void* const* d_in, const int* in_sizes, int n_in,
                              void* d_out, int out_size, void* d_ws, size_t ws_size,
                              hipStream_t stream) {
    const float* x        = (const float*)d_in[0];
    const float* means    = (const float*)d_in[1];
    const float* variance = (const float*)d_in[2];
    float* out = (float*)d_out;

    const size_t xb_elems = (size_t)NB * NF;
    const size_t mb_elems = (size_t)NCP * NF;
    const size_t need = xb_elems * 2 + mb_elems * 2 + (NCP + NB) * 4;

    if (ws_size >= need) {
        ushort* xb = (ushort*)d_ws;
        ushort* mb = xb + xb_elems;
        float* nm = (float*)(mb + mb_elems);
        float* nx = nm + NCP;

        void* args[] = {(void*)&x, (void*)&means, (void*)&variance,
                        (void*)&out, (void*)&xb, (void*)&mb,
                        (void*)&nx, (void*)&nm};
        hipError_t e = hipLaunchCooperativeKernel(
            (const void*)ncm_fused_kernel, dim3(512), dim3(256), args, 0, stream);
        if (e == hipSuccess) return;

        // fallback A: same math, 3 launches
        ncm_prep_kernel<<<(NB + NCP) / 4, 256, 0, stream>>>(
            x, means, variance, xb, mb, nx, nm);
        ncm_gemm_kernel<<<2048, 64, 0, stream>>>(xb, mb, nx, nm, out);
        ncm_softmax_kernel<<<NB, 64, 0, stream>>>(out);
        return;
    }

    // fallback B: no workspace needed
    dim3 g(NB / 32, (NC + 31) / 32);
    ncm_dist_nows_kernel<<<g, 64, 0, stream>>>(x, means, variance, out);
    ncm_softmax_kernel<<<NB, 64, 0, stream>>>(out);
}

// Round 6
// 29.023 us; speedup vs baseline: 4.7717x; 4.7717x over previous
//
#include <hip/hip_runtime.h>
#include <hip/hip_bf16.h>
#include <math.h>

// NCM classifier: B=1024, C=500, F=512 (fp32 in/out).
//   xs = x / variance[0]
//   dist[b][c] = sqrt(sum_f (xs[b][f] - means[c][f])^2)
//   out = concat(softmax(-dist, axis=1), -dist, dist)   // each [B][C]
//
// dist^2 = ||xs||^2 + ||m||^2 - 2*(xs.m), cross term via bf16 MFMA.
// Structure (2 kernels, no grid sync):
//   k1: means -> bf16 ws + exact fp32 norms (512 KB, L3-resident after flush)
//   k2: 256 blocks x 512 thr; block owns 4 b-rows x ALL 512 classes:
//       convert own x rows (no redundancy), MFMA vs streamed bf16 means,
//       in-block softmax -> all three outputs. No cross-block dependency.
#define NB 1024
#define NC 500
#define NCP 512
#define NF 512

typedef __attribute__((ext_vector_type(8))) short bf16x8;
typedef __attribute__((ext_vector_type(4))) float f32x4;

union bfpack { bf16x8 v; __hip_bfloat162 h[4]; };

// ---- k1: means -> bf16 + norms (one wave per row) --------------------------
__global__ __launch_bounds__(256) void ncm_prep_means(
    const float* __restrict__ means, ushort* __restrict__ mb,
    float* __restrict__ nm)
{
    const int lane = threadIdx.x & 63;
    const int c = blockIdx.x * 4 + (threadIdx.x >> 6);   // 0..511
    const bool zero = (c >= NC);

    float4 v0, v1;
    if (!zero) {
        const float* src = means + (size_t)c * NF;
        v0 = *reinterpret_cast<const float4*>(&src[lane * 8]);
        v1 = *reinterpret_cast<const float4*>(&src[lane * 8 + 4]);
    } else {
        v0 = make_float4(0.f, 0.f, 0.f, 0.f);
        v1 = v0;
    }
    bfpack p;
    p.h[0] = __float22bfloat162_rn(make_float2(v0.x, v0.y));
    p.h[1] = __float22bfloat162_rn(make_float2(v0.z, v0.w));
    p.h[2] = __float22bfloat162_rn(make_float2(v1.x, v1.y));
    p.h[3] = __float22bfloat162_rn(make_float2(v1.z, v1.w));
    *reinterpret_cast<bf16x8*>(&mb[(size_t)c * NF + lane * 8]) = p.v;

    float s = v0.x * v0.x + v0.y * v0.y + v0.z * v0.z + v0.w * v0.w
            + v1.x * v1.x + v1.y * v1.y + v1.z * v1.z + v1.w * v1.w;
    #pragma unroll
    for (int off = 32; off > 0; off >>= 1) s += __shfl_xor(s, off, 64);
    if (lane == 0) nm[c] = s;
}

// ---- k2: per-block 4 rows x 512 classes, fused dist + softmax --------------
__global__ __launch_bounds__(512) void ncm_main(
    const float* __restrict__ x, const ushort* __restrict__ mb,
    const float* __restrict__ nm, const float* __restrict__ variance,
    float* __restrict__ out)
{
    __shared__ ushort sA[4][NF];     // own x rows, bf16 (4 KB)
    __shared__ float  sE[4][NCP];    // exponent (-dist) per row (8 KB)
    __shared__ float  sNx[4];        // ||xs||^2 per row

    const int t    = threadIdx.x;
    const int w    = t >> 6;         // wave 0..7
    const int lane = t & 63;
    const int fr   = lane & 15;
    const int g    = lane >> 4;
    const int b0   = blockIdx.x * 4;

    // phase 0: waves 0-3 convert own x rows (scaled) + exact fp32 norms
    if (w < 4) {
        const float* src = x + (size_t)(b0 + w) * NF;
        const float inv_var = 1.0f / variance[0];
        float4 v0 = *reinterpret_cast<const float4*>(&src[lane * 8]);
        float4 v1 = *reinterpret_cast<const float4*>(&src[lane * 8 + 4]);
        v0.x *= inv_var; v0.y *= inv_var; v0.z *= inv_var; v0.w *= inv_var;
        v1.x *= inv_var; v1.y *= inv_var; v1.z *= inv_var; v1.w *= inv_var;
        bfpack p;
        p.h[0] = __float22bfloat162_rn(make_float2(v0.x, v0.y));
        p.h[1] = __float22bfloat162_rn(make_float2(v0.z, v0.w));
        p.h[2] = __float22bfloat162_rn(make_float2(v1.x, v1.y));
        p.h[3] = __float22bfloat162_rn(make_float2(v1.z, v1.w));
        *reinterpret_cast<bf16x8*>(&sA[w][lane * 8]) = p.v;
        float s = v0.x * v0.x + v0.y * v0.y + v0.z * v0.z + v0.w * v0.w
                + v1.x * v1.x + v1.y * v1.y + v1.z * v1.z + v1.w * v1.w;
        #pragma unroll
        for (int off = 32; off > 0; off >>= 1) s += __shfl_xor(s, off, 64);
        if (lane == 0) sNx[w] = s;
    }
    __syncthreads();

    // A fragments to registers once: row fr -> x row (fr&3) (4x duplicated)
    bf16x8 a[16];
    #pragma unroll
    for (int ks = 0; ks < 16; ++ks)
        a[ks] = *reinterpret_cast<const bf16x8*>(&sA[fr & 3][ks * 32 + g * 8]);

    const float nx0 = sNx[0], nx1 = sNx[1], nx2 = sNx[2], nx3 = sNx[3];

    // phase 1: wave w covers classes [w*64, w*64+64) as 4 tiles, 2 pairs
    #pragma unroll
    for (int p = 0; p < 2; ++p) {
        const int c0 = w * 64 + p * 32;
        const ushort* bp0 = mb + (size_t)(c0 + fr) * NF + g * 8;
        const ushort* bp1 = bp0 + (size_t)16 * NF;

        f32x4 acc0 = {0.f, 0.f, 0.f, 0.f};
        f32x4 acc1 = acc0;
        #pragma unroll
        for (int ks = 0; ks < 16; ++ks) {
            bf16x8 q0 = *reinterpret_cast<const bf16x8*>(bp0 + ks * 32);
            bf16x8 q1 = *reinterpret_cast<const bf16x8*>(bp1 + ks * 32);
            acc0 = __builtin_amdgcn_mfma_f32_16x16x32_bf16(a[ks], q0, acc0, 0, 0, 0);
            acc1 = __builtin_amdgcn_mfma_f32_16x16x32_bf16(a[ks], q1, acc1, 0, 0, 0);
        }

        // D row (g*4+r) maps to x row ((g*4+r)&3) = r, so g==0 lanes hold
        // rows 0..3 directly (other g-groups are duplicates).
        if (g == 0) {
            const int cA = c0 + fr, cB = cA + 16;
            const float nmA = nm[cA], nmB = nm[cB];
            const float nx[4] = {nx0, nx1, nx2, nx3};
            #pragma unroll
            for (int r = 0; r < 4; ++r) {
                float dA = sqrtf(fmaxf(nx[r] + nmA - 2.0f * acc0[r], 0.0f));
                float dB = sqrtf(fmaxf(nx[r] + nmB - 2.0f * acc1[r], 0.0f));
                sE[r][cA] = (cA < NC) ? -dA : -1e30f;
                sE[r][cB] = (cB < NC) ? -dB : -1e30f;
            }
        }
    }
    __syncthreads();

    // phase 2: waves 0-3 softmax row w from LDS, write all three outputs
    if (w < 4) {
        const int b = b0 + w;
        const int base = lane * 8;
        float4 v0 = *reinterpret_cast<const float4*>(&sE[w][base]);
        float4 v1 = *reinterpret_cast<const float4*>(&sE[w][base + 4]);

        float m = fmaxf(fmaxf(fmaxf(v0.x, v0.y), fmaxf(v0.z, v0.w)),
                        fmaxf(fmaxf(v1.x, v1.y), fmaxf(v1.z, v1.w)));
        #pragma unroll
        for (int off = 32; off > 0; off >>= 1)
            m = fmaxf(m, __shfl_xor(m, off, 64));

        float4 e0, e1;
        e0.x = expf(v0.x - m); e0.y = expf(v0.y - m);
        e0.z = expf(v0.z - m); e0.w = expf(v0.w - m);
        e1.x = expf(v1.x - m); e1.y = expf(v1.y - m);
        e1.z = expf(v1.z - m); e1.w = expf(v1.w - m);

        float s = e0.x + e0.y + e0.z + e0.w + e1.x + e1.y + e1.z + e1.w;
        #pragma unroll
        for (int off = 32; off > 0; off >>= 1)
            s += __shfl_xor(s, off, 64);
        const float inv = 1.0f / s;
        e0.x *= inv; e0.y *= inv; e0.z *= inv; e0.w *= inv;
        e1.x *= inv; e1.y *= inv; e1.z *= inv; e1.w *= inv;

        float* probs = out + (size_t)b * NC;
        float* expo  = out + (size_t)NB * NC + (size_t)b * NC;
        float* cdiff = out + (size_t)2 * NB * NC + (size_t)b * NC;

        const bool val0 = base + 3 < NC;   // lanes 0..62
        const bool val1 = base + 7 < NC;   // lanes 0..61
        if (val0) {
            *reinterpret_cast<float4*>(&probs[base]) = e0;
            float4 ex = v0;
            *reinterpret_cast<float4*>(&expo[base]) = ex;
            float4 cd = make_float4(-ex.x, -ex.y, -ex.z, -ex.w);
            *reinterpret_cast<float4*>(&cdiff[base]) = cd;
        }
        if (val1) {
            *reinterpret_cast<float4*>(&probs[base + 4]) = e1;
            float4 ex = v1;
            *reinterpret_cast<float4*>(&expo[base + 4]) = ex;
            float4 cd = make_float4(-ex.x, -ex.y, -ex.z, -ex.w);
            *reinterpret_cast<float4*>(&cdiff[base + 4]) = cd;
        }
    }
}

// ---- fallback (no ws): R4's proven no-ws path ------------------------------
static __device__ inline bf16x8 cvt8(float4 u0, float4 u1, float scale, float& nacc) {
    u0.x *= scale; u0.y *= scale; u0.z *= scale; u0.w *= scale;
    u1.x *= scale; u1.y *= scale; u1.z *= scale; u1.w *= scale;
    bfpack p;
    p.h[0] = __float22bfloat162_rn(make_float2(u0.x, u0.y));
    p.h[1] = __float22bfloat162_rn(make_float2(u0.z, u0.w));
    p.h[2] = __float22bfloat162_rn(make_float2(u1.x, u1.y));
    p.h[3] = __float22bfloat162_rn(make_float2(u1.z, u1.w));
    nacc = fmaf(u0.x, u0.x, nacc); nacc = fmaf(u0.y, u0.y, nacc);
    nacc = fmaf(u0.z, u0.z, nacc); nacc = fmaf(u0.w, u0.w, nacc);
    nacc = fmaf(u1.x, u1.x, nacc); nacc = fmaf(u1.y, u1.y, nacc);
    nacc = fmaf(u1.z, u1.z, nacc); nacc = fmaf(u1.w, u1.w, nacc);
    return p.v;
}

__global__ __launch_bounds__(64) void ncm_dist_nows_kernel(
    const float* __restrict__ x, const float* __restrict__ means,
    const float* __restrict__ variance, float* __restrict__ out)
{
    const int lane = threadIdx.x;
    const int g  = lane >> 4;
    const int fr = lane & 15;
    const int b0 = blockIdx.x * 32;
    const int c0 = blockIdx.y * 32;
    const float inv_var = 1.0f / variance[0];

    const float* pa0 = x + (size_t)(b0 + fr) * NF + g * 8;
    const float* pa1 = pa0 + (size_t)16 * NF;
    const int cB0 = c0 + fr, cB1 = cB0 + 16;
    const bool vB0 = cB0 < NC, vB1 = cB1 < NC;
    const float* pb0 = means + (size_t)cB0 * NF + g * 8;
    const float* pb1 = means + (size_t)cB1 * NF + g * 8;

    f32x4 acc00 = {0.f, 0.f, 0.f, 0.f};
    f32x4 acc01 = acc00, acc10 = acc00, acc11 = acc00;
    float na0 = 0.f, na1 = 0.f, nb0 = 0.f, nb1 = 0.f;
    const float4 z4 = make_float4(0.f, 0.f, 0.f, 0.f);

    #pragma unroll 4
    for (int k = 0; k < NF; k += 32) {
        float4 a0lo = *reinterpret_cast<const float4*>(pa0 + k);
        float4 a0hi = *reinterpret_cast<const float4*>(pa0 + k + 4);
        float4 a1lo = *reinterpret_cast<const float4*>(pa1 + k);
        float4 a1hi = *reinterpret_cast<const float4*>(pa1 + k + 4);
        float4 b0lo = vB0 ? *reinterpret_cast<const float4*>(pb0 + k)     : z4;
        float4 b0hi = vB0 ? *reinterpret_cast<const float4*>(pb0 + k + 4) : z4;
        float4 b1lo = vB1 ? *reinterpret_cast<const float4*>(pb1 + k)     : z4;
        float4 b1hi = vB1 ? *reinterpret_cast<const float4*>(pb1 + k + 4) : z4;

        bf16x8 fa0 = cvt8(a0lo, a0hi, inv_var, na0);
        bf16x8 fa1 = cvt8(a1lo, a1hi, inv_var, na1);
        bf16x8 fb0 = cvt8(b0lo, b0hi, 1.0f, nb0);
        bf16x8 fb1 = cvt8(b1lo, b1hi, 1.0f, nb1);

        acc00 = __builtin_amdgcn_mfma_f32_16x16x32_bf16(fa0, fb0, acc00, 0, 0, 0);
        acc01 = __builtin_amdgcn_mfma_f32_16x16x32_bf16(fa0, fb1, acc01, 0, 0, 0);
        acc10 = __builtin_amdgcn_mfma_f32_16x16x32_bf16(fa1, fb0, acc10, 0, 0, 0);
        acc11 = __builtin_amdgcn_mfma_f32_16x16x32_bf16(fa1, fb1, acc11, 0, 0, 0);
    }

    na0 += __shfl_xor(na0, 16, 64); na0 += __shfl_xor(na0, 32, 64);
    na1 += __shfl_xor(na1, 16, 64); na1 += __shfl_xor(na1, 32, 64);
    nb0 += __shfl_xor(nb0, 16, 64); nb0 += __shfl_xor(nb0, 32, 64);
    nb1 += __shfl_xor(nb1, 16, 64); nb1 += __shfl_xor(nb1, 32, 64);

    const int rg = g * 4;
    float nxr0[4], nxr1[4];
    #pragma unroll
    for (int r = 0; r < 4; ++r) {
        nxr0[r] = __shfl(na0, rg + r, 64);
        nxr1[r] = __shfl(na1, rg + r, 64);
    }

    float* expo  = out + (size_t)NB * NC;
    float* cdiff = out + (size_t)2 * NB * NC;
    #pragma unroll
    for (int wm = 0; wm < 2; ++wm) {
        f32x4 g_lo = wm ? acc10 : acc00;
        f32x4 g_hi = wm ? acc11 : acc01;
        #pragma unroll
        for (int r = 0; r < 4; ++r) {
            int b = b0 + wm * 16 + rg + r;
            float nxb = wm ? nxr1[r] : nxr0[r];
            if (vB0) {
                float d = sqrtf(fmaxf(nxb + nb0 - 2.0f * g_lo[r], 0.0f));
                expo[(size_t)b * NC + cB0]  = -d;
                cdiff[(size_t)b * NC + cB0] = d;
            }
            if (vB1) {
                float d = sqrtf(fmaxf(nxb + nb1 - 2.0f * g_hi[r], 0.0f));
                expo[(size_t)b * NC + cB1]  = -d;
                cdiff[(size_t)b * NC + cB1] = d;
            }
        }
    }
}

__global__ __launch_bounds__(64) void ncm_softmax_kernel(float* __restrict__ out)
{
    const int b = blockIdx.x;
    const int lane = threadIdx.x;
    const float* expo = out + (size_t)NB * NC + (size_t)b * NC;
    float* probs = out + (size_t)b * NC;

    const int base = lane * 8;
    const bool val0 = base + 3 < NC;
    const bool val1 = base + 7 < NC;
    const float4 ninf = make_float4(-1e30f, -1e30f, -1e30f, -1e30f);

    float4 v0 = val0 ? *reinterpret_cast<const float4*>(&expo[base])     : ninf;
    float4 v1 = val1 ? *reinterpret_cast<const float4*>(&expo[base + 4]) : ninf;

    float m = fmaxf(fmaxf(fmaxf(v0.x, v0.y), fmaxf(v0.z, v0.w)),
                    fmaxf(fmaxf(v1.x, v1.y), fmaxf(v1.z, v1.w)));
    #pragma unroll
    for (int off = 32; off > 0; off >>= 1)
        m = fmaxf(m, __shfl_xor(m, off, 64));

    float4 e0, e1;
    e0.x = expf(v0.x - m); e0.y = expf(v0.y - m);
    e0.z = expf(v0.z - m); e0.w = expf(v0.w - m);
    e1.x = expf(v1.x - m); e1.y = expf(v1.y - m);
    e1.z = expf(v1.z - m); e1.w = expf(v1.w - m);

    float s = e0.x + e0.y + e0.z + e0.w + e1.x + e1.y + e1.z + e1.w;
    #pragma unroll
    for (int off = 32; off > 0; off >>= 1)
        s += __shfl_xor(s, off, 64);
    float inv = 1.0f / s;

    e0.x *= inv; e0.y *= inv; e0.z *= inv; e0.w *= inv;
    e1.x *= inv; e1.y *= inv; e1.z *= inv; e1.w *= inv;

    if (val0) *reinterpret_cast<float4*>(&probs[base])     = e0;
    if (val1) *reinterpret_cast<float4*>(&probs[base + 4]) = e1;
}

extern "C" void kernel_launch(void* const* d_in, const int* in_sizes, int n_in,
                              void* d_out, int out_size, void* d_ws, size_t ws_size,
                              hipStream_t stream) {
    const float* x        = (const float*)d_in[0];
    const float* means    = (const float*)d_in[1];
    const float* variance = (const float*)d_in[2];
    float* out = (float*)d_out;

    const size_t mb_elems = (size_t)NCP * NF;
    const size_t need = mb_elems * 2 + NCP * 4;   // 512 KB + 2 KB

    if (ws_size >= need) {
        ushort* mb = (ushort*)d_ws;
        float* nm = (float*)(mb + mb_elems);

        ncm_prep_means<<<NCP / 4, 256, 0, stream>>>(means, mb, nm);
        ncm_main<<<NB / 4, 512, 0, stream>>>(x, mb, nm, variance, out);
        return;
    }

    // fallback: no workspace
    dim3 g(NB / 32, (NC + 31) / 32);
    ncm_dist_nows_kernel<<<g, 64, 0, stream>>>(x, means, variance, out);
    ncm_softmax_kernel<<<NB, 64, 0, stream>>>(out);
}

// Round 7
// 23.439 us; speedup vs baseline: 5.9084x; 1.2382x over previous
//
#include <hip/hip_runtime.h>
#include <hip/hip_bf16.h>
#include <math.h>

// NCM classifier: B=1024, C=500, F=512 (fp32 in/out).
//   xs = x / variance[0]
//   dist[b][c] = sqrt(sum_f (xs[b][f] - means[c][f])^2)
//   out = concat(softmax(-dist, axis=1), -dist, dist)   // each [B][C]
//
// dist^2 = ||xs||^2 + ||m||^2 - 2*(xs.m), cross term via bf16 MFMA (K=512).
// R3 3-kernel structure (empirical best), GEMM re-packed for occupancy:
//   k1 prep: x,means -> bf16 ws + exact fp32 norms (1536 rows)
//   k2 gemm: 256 blocks x 512 thr; 8 waves/CU (vs R3's 2); wave = 16x16 tile,
//            block tile 32x64, full-K unroll -> 32 loads in flight
//   k3 softmax: one wave per row
#define NB 1024
#define NC 500
#define NCP 512
#define NF 512

typedef __attribute__((ext_vector_type(8))) short bf16x8;
typedef __attribute__((ext_vector_type(4))) float f32x4;

union bfpack { bf16x8 v; __hip_bfloat162 h[4]; };

// ---- k1: fp32 -> bf16 + row norms (one wave per row, 1536 rows) ------------
__global__ __launch_bounds__(256) void ncm_prep_kernel(
    const float* __restrict__ x, const float* __restrict__ means,
    const float* __restrict__ variance,
    ushort* __restrict__ xb, ushort* __restrict__ mb,
    float* __restrict__ nx, float* __restrict__ nm)
{
    const int lane = threadIdx.x & 63;
    const int wid  = blockIdx.x * 4 + (threadIdx.x >> 6);  // 0..1535

    const float* src;
    ushort* dst;
    float* nrm;
    float scale;
    bool zero = false;
    if (wid < NB) {
        src = x + (size_t)wid * NF;   dst = xb + (size_t)wid * NF;
        nrm = nx + wid;               scale = 1.0f / variance[0];
    } else {
        int c = wid - NB;
        src = means + (size_t)c * NF; dst = mb + (size_t)c * NF;
        nrm = nm + c;                 scale = 1.0f;
        zero = (c >= NC);
    }

    float4 v0, v1;
    if (!zero) {
        v0 = *reinterpret_cast<const float4*>(&src[lane * 8]);
        v1 = *reinterpret_cast<const float4*>(&src[lane * 8 + 4]);
        v0.x *= scale; v0.y *= scale; v0.z *= scale; v0.w *= scale;
        v1.x *= scale; v1.y *= scale; v1.z *= scale; v1.w *= scale;
    } else {
        v0 = make_float4(0.f, 0.f, 0.f, 0.f);
        v1 = v0;
    }
    bfpack p;
    p.h[0] = __float22bfloat162_rn(make_float2(v0.x, v0.y));
    p.h[1] = __float22bfloat162_rn(make_float2(v0.z, v0.w));
    p.h[2] = __float22bfloat162_rn(make_float2(v1.x, v1.y));
    p.h[3] = __float22bfloat162_rn(make_float2(v1.z, v1.w));
    *reinterpret_cast<bf16x8*>(&dst[lane * 8]) = p.v;

    float s = v0.x * v0.x + v0.y * v0.y + v0.z * v0.z + v0.w * v0.w
            + v1.x * v1.x + v1.y * v1.y + v1.z * v1.z + v1.w * v1.w;
    #pragma unroll
    for (int off = 32; off > 0; off >>= 1) s += __shfl_xor(s, off, 64);
    if (lane == 0) *nrm = s;
}

// ---- k2: GEMM + distance epilogue ------------------------------------------
// grid (32, 8) = 256 blocks x 512 thr: block tile 32(b) x 64(c), 8 waves,
// wave w -> quadrant (w>>2, w&3), each wave one 16x16 MFMA tile, full-K.
__global__ __launch_bounds__(512) void ncm_gemm_kernel(
    const ushort* __restrict__ xb, const ushort* __restrict__ mb,
    const float* __restrict__ nx, const float* __restrict__ nm,
    float* __restrict__ out)
{
    const int t    = threadIdx.x;
    const int w    = t >> 6;
    const int lane = t & 63;
    const int fr   = lane & 15;
    const int g    = lane >> 4;

    const int b0 = blockIdx.x * 32 + (w >> 2) * 16;
    const int c0 = blockIdx.y * 64 + (w & 3) * 16;

    const ushort* ap = xb + (size_t)(b0 + fr) * NF + g * 8;
    const ushort* bp = mb + (size_t)(c0 + fr) * NF + g * 8;

    f32x4 acc = {0.f, 0.f, 0.f, 0.f};
    #pragma unroll
    for (int ks = 0; ks < 16; ++ks) {
        bf16x8 a = *reinterpret_cast<const bf16x8*>(ap + ks * 32);
        bf16x8 b = *reinterpret_cast<const bf16x8*>(bp + ks * 32);
        acc = __builtin_amdgcn_mfma_f32_16x16x32_bf16(a, b, acc, 0, 0, 0);
    }

    // C/D layout (m89/m91): col = lane&15 -> class c0+fr; row = g*4+r -> b
    const int c = c0 + fr;
    if (c < NC) {
        const float nmc = nm[c];
        float* expo  = out + (size_t)NB * NC;
        float* cdiff = out + (size_t)2 * NB * NC;
        #pragma unroll
        for (int r = 0; r < 4; ++r) {
            const int b = b0 + g * 4 + r;
            float d2 = nx[b] + nmc - 2.0f * acc[r];
            float d = sqrtf(fmaxf(d2, 0.0f));
            expo[(size_t)b * NC + c]  = -d;
            cdiff[(size_t)b * NC + c] = d;
        }
    }
}

// ---- k3: softmax over C=500, one wave per row ------------------------------
__global__ __launch_bounds__(64) void ncm_softmax_kernel(float* __restrict__ out)
{
    const int b = blockIdx.x;
    const int lane = threadIdx.x;
    const float* expo = out + (size_t)NB * NC + (size_t)b * NC;
    float* probs = out + (size_t)b * NC;

    const int base = lane * 8;
    const bool val0 = base + 3 < NC;   // lanes 0..62
    const bool val1 = base + 7 < NC;   // lanes 0..61
    const float4 ninf = make_float4(-1e30f, -1e30f, -1e30f, -1e30f);

    float4 v0 = val0 ? *reinterpret_cast<const float4*>(&expo[base])     : ninf;
    float4 v1 = val1 ? *reinterpret_cast<const float4*>(&expo[base + 4]) : ninf;

    float m = fmaxf(fmaxf(fmaxf(v0.x, v0.y), fmaxf(v0.z, v0.w)),
                    fmaxf(fmaxf(v1.x, v1.y), fmaxf(v1.z, v1.w)));
    #pragma unroll
    for (int off = 32; off > 0; off >>= 1)
        m = fmaxf(m, __shfl_xor(m, off, 64));

    float4 e0, e1;
    e0.x = expf(v0.x - m); e0.y = expf(v0.y - m);
    e0.z = expf(v0.z - m); e0.w = expf(v0.w - m);
    e1.x = expf(v1.x - m); e1.y = expf(v1.y - m);
    e1.z = expf(v1.z - m); e1.w = expf(v1.w - m);

    float s = e0.x + e0.y + e0.z + e0.w + e1.x + e1.y + e1.z + e1.w;
    #pragma unroll
    for (int off = 32; off > 0; off >>= 1)
        s += __shfl_xor(s, off, 64);
    float inv = 1.0f / s;

    e0.x *= inv; e0.y *= inv; e0.z *= inv; e0.w *= inv;
    e1.x *= inv; e1.y *= inv; e1.z *= inv; e1.w *= inv;

    if (val0) *reinterpret_cast<float4*>(&probs[base])     = e0;
    if (val1) *reinterpret_cast<float4*>(&probs[base + 4]) = e1;
}

// ---- fallback (no ws): R4's proven no-ws path ------------------------------
static __device__ inline bf16x8 cvt8(float4 u0, float4 u1, float scale, float& nacc) {
    u0.x *= scale; u0.y *= scale; u0.z *= scale; u0.w *= scale;
    u1.x *= scale; u1.y *= scale; u1.z *= scale; u1.w *= scale;
    bfpack p;
    p.h[0] = __float22bfloat162_rn(make_float2(u0.x, u0.y));
    p.h[1] = __float22bfloat162_rn(make_float2(u0.z, u0.w));
    p.h[2] = __float22bfloat162_rn(make_float2(u1.x, u1.y));
    p.h[3] = __float22bfloat162_rn(make_float2(u1.z, u1.w));
    nacc = fmaf(u0.x, u0.x, nacc); nacc = fmaf(u0.y, u0.y, nacc);
    nacc = fmaf(u0.z, u0.z, nacc); nacc = fmaf(u0.w, u0.w, nacc);
    nacc = fmaf(u1.x, u1.x, nacc); nacc = fmaf(u1.y, u1.y, nacc);
    nacc = fmaf(u1.z, u1.z, nacc); nacc = fmaf(u1.w, u1.w, nacc);
    return p.v;
}

__global__ __launch_bounds__(64) void ncm_dist_nows_kernel(
    const float* __restrict__ x, const float* __restrict__ means,
    const float* __restrict__ variance, float* __restrict__ out)
{
    const int lane = threadIdx.x;
    const int g  = lane >> 4;
    const int fr = lane & 15;
    const int b0 = blockIdx.x * 32;
    const int c0 = blockIdx.y * 32;
    const float inv_var = 1.0f / variance[0];

    const float* pa0 = x + (size_t)(b0 + fr) * NF + g * 8;
    const float* pa1 = pa0 + (size_t)16 * NF;
    const int cB0 = c0 + fr, cB1 = cB0 + 16;
    const bool vB0 = cB0 < NC, vB1 = cB1 < NC;
    const float* pb0 = means + (size_t)cB0 * NF + g * 8;
    const float* pb1 = means + (size_t)cB1 * NF + g * 8;

    f32x4 acc00 = {0.f, 0.f, 0.f, 0.f};
    f32x4 acc01 = acc00, acc10 = acc00, acc11 = acc00;
    float na0 = 0.f, na1 = 0.f, nb0 = 0.f, nb1 = 0.f;
    const float4 z4 = make_float4(0.f, 0.f, 0.f, 0.f);

    #pragma unroll 4
    for (int k = 0; k < NF; k += 32) {
        float4 a0lo = *reinterpret_cast<const float4*>(pa0 + k);
        float4 a0hi = *reinterpret_cast<const float4*>(pa0 + k + 4);
        float4 a1lo = *reinterpret_cast<const float4*>(pa1 + k);
        float4 a1hi = *reinterpret_cast<const float4*>(pa1 + k + 4);
        float4 b0lo = vB0 ? *reinterpret_cast<const float4*>(pb0 + k)     : z4;
        float4 b0hi = vB0 ? *reinterpret_cast<const float4*>(pb0 + k + 4) : z4;
        float4 b1lo = vB1 ? *reinterpret_cast<const float4*>(pb1 + k)     : z4;
        float4 b1hi = vB1 ? *reinterpret_cast<const float4*>(pb1 + k + 4) : z4;

        bf16x8 fa0 = cvt8(a0lo, a0hi, inv_var, na0);
        bf16x8 fa1 = cvt8(a1lo, a1hi, inv_var, na1);
        bf16x8 fb0 = cvt8(b0lo, b0hi, 1.0f, nb0);
        bf16x8 fb1 = cvt8(b1lo, b1hi, 1.0f, nb1);

        acc00 = __builtin_amdgcn_mfma_f32_16x16x32_bf16(fa0, fb0, acc00, 0, 0, 0);
        acc01 = __builtin_amdgcn_mfma_f32_16x16x32_bf16(fa0, fb1, acc01, 0, 0, 0);
        acc10 = __builtin_amdgcn_mfma_f32_16x16x32_bf16(fa1, fb0, acc10, 0, 0, 0);
        acc11 = __builtin_amdgcn_mfma_f32_16x16x32_bf16(fa1, fb1, acc11, 0, 0, 0);
    }

    na0 += __shfl_xor(na0, 16, 64); na0 += __shfl_xor(na0, 32, 64);
    na1 += __shfl_xor(na1, 16, 64); na1 += __shfl_xor(na1, 32, 64);
    nb0 += __shfl_xor(nb0, 16, 64); nb0 += __shfl_xor(nb0, 32, 64);
    nb1 += __shfl_xor(nb1, 16, 64); nb1 += __shfl_xor(nb1, 32, 64);

    const int rg = g * 4;
    float nxr0[4], nxr1[4];
    #pragma unroll
    for (int r = 0; r < 4; ++r) {
        nxr0[r] = __shfl(na0, rg + r, 64);
        nxr1[r] = __shfl(na1, rg + r, 64);
    }

    float* expo  = out + (size_t)NB * NC;
    float* cdiff = out + (size_t)2 * NB * NC;
    #pragma unroll
    for (int wm = 0; wm < 2; ++wm) {
        f32x4 g_lo = wm ? acc10 : acc00;
        f32x4 g_hi = wm ? acc11 : acc01;
        #pragma unroll
        for (int r = 0; r < 4; ++r) {
            int b = b0 + wm * 16 + rg + r;
            float nxb = wm ? nxr1[r] : nxr0[r];
            if (vB0) {
                float d = sqrtf(fmaxf(nxb + nb0 - 2.0f * g_lo[r], 0.0f));
                expo[(size_t)b * NC + cB0]  = -d;
                cdiff[(size_t)b * NC + cB0] = d;
            }
            if (vB1) {
                float d = sqrtf(fmaxf(nxb + nb1 - 2.0f * g_hi[r], 0.0f));
                expo[(size_t)b * NC + cB1]  = -d;
                cdiff[(size_t)b * NC + cB1] = d;
            }
        }
    }
}

extern "C" void kernel_launch(void* const* d_in, const int* in_sizes, int n_in,
                              void* d_out, int out_size, void* d_ws, size_t ws_size,
                              hipStream_t stream) {
    const float* x        = (const float*)d_in[0];
    const float* means    = (const float*)d_in[1];
    const float* variance = (const float*)d_in[2];
    float* out = (float*)d_out;

    const size_t xb_elems = (size_t)NB * NF;
    const size_t mb_elems = (size_t)NCP * NF;
    const size_t need = xb_elems * 2 + mb_elems * 2 + (NCP + NB) * 4;

    if (ws_size >= need) {
        ushort* xb = (ushort*)d_ws;
        ushort* mb = xb + xb_elems;
        float* nm = (float*)(mb + mb_elems);
        float* nx = nm + NCP;

        ncm_prep_kernel<<<(NB + NCP) / 4, 256, 0, stream>>>(
            x, means, variance, xb, mb, nx, nm);
        dim3 g(NB / 32, NCP / 64);   // (32, 8) = 256 blocks, 8 waves each
        ncm_gemm_kernel<<<g, 512, 0, stream>>>(xb, mb, nx, nm, out);
        ncm_softmax_kernel<<<NB, 64, 0, stream>>>(out);
        return;
    }

    // fallback: no workspace
    dim3 g(NB / 32, (NC + 31) / 32);
    ncm_dist_nows_kernel<<<g, 64, 0, stream>>>(x, means, variance, out);
    ncm_softmax_kernel<<<NB, 64, 0, stream>>>(out);
}

// Round 8
// 17.759 us; speedup vs baseline: 7.7982x; 1.3199x over previous
//
#include <hip/hip_runtime.h>
#include <hip/hip_bf16.h>
#include <math.h>

// NCM classifier: B=1024, C=500, F=512 (fp32 in/out).
//   xs = x / variance[0]
//   dist[b][c] = sqrt(sum_f (xs[b][f] - means[c][f])^2)
//   out = concat(softmax(-dist, axis=1), -dist, dist)   // each [B][C]
//
// dist^2 = ||xs||^2 + ||m||^2 - 2*(xs.m), cross term via bf16 MFMA (K=512).
// 2 kernels, no workspace:
//   k1: fused dist — per-block LDS staging (fp32->bf16 convert + exact fp32
//       norms), then 16x16 MFMA tiles from LDS, epilogue writes -dist/dist.
//       Block = 32 b-rows x 64 classes, 8 waves, grid (32,8) -> 1 block/CU.
//   k2: softmax, one wave per row.
#define NB 1024
#define NC 500
#define NCP 512
#define NF 512
#define LSTR 520   // LDS row stride in bf16 elems: 1040 B, 16B-aligned,
                   // +260 words/row -> +4 banks/row -> uniform bank spread

typedef __attribute__((ext_vector_type(8))) short bf16x8;
typedef __attribute__((ext_vector_type(4))) float f32x4;

union bfpack { bf16x8 v; __hip_bfloat162 h[4]; };

// ---- k1: fused stage + GEMM + distance epilogue ----------------------------
__global__ __launch_bounds__(512) void ncm_dist_fused(
    const float* __restrict__ x, const float* __restrict__ means,
    const float* __restrict__ variance, float* __restrict__ out)
{
    __shared__ ushort sA[32][LSTR];   // x rows (bf16, scaled)   65.0 KB
    __shared__ ushort sB[64][LSTR];   // means rows (bf16)       (A+B = 99.8 KB)
    __shared__ float  sNx[32];        // ||xs||^2 (exact fp32)
    __shared__ float  sNm[64];        // ||m||^2  (exact fp32)

    const int t    = threadIdx.x;
    const int w    = t >> 6;          // wave 0..7
    const int lane = t & 63;
    const int fr   = lane & 15;
    const int g    = lane >> 4;
    const int b0   = blockIdx.x * 32;
    const int c0   = blockIdx.y * 64;
    const float inv_var = 1.0f / variance[0];

    // ---- stage: 96 rows (32 x + 64 means), 12 rows per wave ----
    #pragma unroll
    for (int j = 0; j < 12; ++j) {
        const int ri = w * 12 + j;            // 0..95
        const float* src;
        ushort* dst;
        float* nrm;
        float scale;
        bool zero = false;
        if (ri < 32) {
            src = x + (size_t)(b0 + ri) * NF;  dst = &sA[ri][0];
            nrm = &sNx[ri];                    scale = inv_var;
        } else {
            const int cm = c0 + ri - 32;
            src = means + (size_t)cm * NF;     dst = &sB[ri - 32][0];
            nrm = &sNm[ri - 32];               scale = 1.0f;
            zero = (cm >= NC);
        }

        float4 v0, v1;
        if (!zero) {
            v0 = *reinterpret_cast<const float4*>(&src[lane * 8]);
            v1 = *reinterpret_cast<const float4*>(&src[lane * 8 + 4]);
            v0.x *= scale; v0.y *= scale; v0.z *= scale; v0.w *= scale;
            v1.x *= scale; v1.y *= scale; v1.z *= scale; v1.w *= scale;
        } else {
            v0 = make_float4(0.f, 0.f, 0.f, 0.f);
            v1 = v0;
        }
        bfpack p;
        p.h[0] = __float22bfloat162_rn(make_float2(v0.x, v0.y));
        p.h[1] = __float22bfloat162_rn(make_float2(v0.z, v0.w));
        p.h[2] = __float22bfloat162_rn(make_float2(v1.x, v1.y));
        p.h[3] = __float22bfloat162_rn(make_float2(v1.z, v1.w));
        *reinterpret_cast<bf16x8*>(&dst[lane * 8]) = p.v;

        float s = v0.x * v0.x + v0.y * v0.y + v0.z * v0.z + v0.w * v0.w
                + v1.x * v1.x + v1.y * v1.y + v1.z * v1.z + v1.w * v1.w;
        #pragma unroll
        for (int off = 32; off > 0; off >>= 1) s += __shfl_xor(s, off, 64);
        if (lane == 0) *nrm = s;
    }
    __syncthreads();

    // ---- MFMA: wave w -> 16x16 tile at (b-half w>>2, c-quarter w&3) ----
    const int ar = (w >> 2) * 16 + fr;    // local A row
    const int br = (w & 3) * 16 + fr;     // local B row
    const ushort* ap = &sA[ar][g * 8];
    const ushort* bp = &sB[br][g * 8];

    f32x4 acc = {0.f, 0.f, 0.f, 0.f};
    #pragma unroll
    for (int ks = 0; ks < 16; ++ks) {
        bf16x8 a = *reinterpret_cast<const bf16x8*>(ap + ks * 32);
        bf16x8 b = *reinterpret_cast<const bf16x8*>(bp + ks * 32);
        acc = __builtin_amdgcn_mfma_f32_16x16x32_bf16(a, b, acc, 0, 0, 0);
    }

    // C/D layout (m89/m91): col = lane&15 -> class, row = g*4+r -> b-row
    const int c = c0 + (w & 3) * 16 + fr;
    if (c < NC) {
        const float nmc = sNm[(w & 3) * 16 + fr];
        float* expo  = out + (size_t)NB * NC;
        float* cdiff = out + (size_t)2 * NB * NC;
        #pragma unroll
        for (int r = 0; r < 4; ++r) {
            const int bl = (w >> 2) * 16 + g * 4 + r;   // local b row
            const int b  = b0 + bl;
            float d2 = sNx[bl] + nmc - 2.0f * acc[r];
            float d = sqrtf(fmaxf(d2, 0.0f));
            expo[(size_t)b * NC + c]  = -d;
            cdiff[(size_t)b * NC + c] = d;
        }
    }
}

// ---- k2: softmax over C=500, one wave per row ------------------------------
__global__ __launch_bounds__(64) void ncm_softmax_kernel(float* __restrict__ out)
{
    const int b = blockIdx.x;
    const int lane = threadIdx.x;
    const float* expo = out + (size_t)NB * NC + (size_t)b * NC;
    float* probs = out + (size_t)b * NC;

    const int base = lane * 8;
    const bool val0 = base + 3 < NC;   // lanes 0..62
    const bool val1 = base + 7 < NC;   // lanes 0..61
    const float4 ninf = make_float4(-1e30f, -1e30f, -1e30f, -1e30f);

    float4 v0 = val0 ? *reinterpret_cast<const float4*>(&expo[base])     : ninf;
    float4 v1 = val1 ? *reinterpret_cast<const float4*>(&expo[base + 4]) : ninf;

    float m = fmaxf(fmaxf(fmaxf(v0.x, v0.y), fmaxf(v0.z, v0.w)),
                    fmaxf(fmaxf(v1.x, v1.y), fmaxf(v1.z, v1.w)));
    #pragma unroll
    for (int off = 32; off > 0; off >>= 1)
        m = fmaxf(m, __shfl_xor(m, off, 64));

    float4 e0, e1;
    e0.x = expf(v0.x - m); e0.y = expf(v0.y - m);
    e0.z = expf(v0.z - m); e0.w = expf(v0.w - m);
    e1.x = expf(v1.x - m); e1.y = expf(v1.y - m);
    e1.z = expf(v1.z - m); e1.w = expf(v1.w - m);

    float s = e0.x + e0.y + e0.z + e0.w + e1.x + e1.y + e1.z + e1.w;
    #pragma unroll
    for (int off = 32; off > 0; off >>= 1)
        s += __shfl_xor(s, off, 64);
    float inv = 1.0f / s;

    e0.x *= inv; e0.y *= inv; e0.z *= inv; e0.w *= inv;
    e1.x *= inv; e1.y *= inv; e1.z *= inv; e1.w *= inv;

    if (val0) *reinterpret_cast<float4*>(&probs[base])     = e0;
    if (val1) *reinterpret_cast<float4*>(&probs[base + 4]) = e1;
}

extern "C" void kernel_launch(void* const* d_in, const int* in_sizes, int n_in,
                              void* d_out, int out_size, void* d_ws, size_t ws_size,
                              hipStream_t stream) {
    const float* x        = (const float*)d_in[0];
    const float* means    = (const float*)d_in[1];
    const float* variance = (const float*)d_in[2];
    float* out = (float*)d_out;

    dim3 g(NB / 32, NCP / 64);   // (32, 8) = 256 blocks, 8 waves, 1 block/CU
    ncm_dist_fused<<<g, 512, 0, stream>>>(x, means, variance, out);
    ncm_softmax_kernel<<<NB, 64, 0, stream>>>(out);
}